// Round 1
// baseline (553.534 us; speedup 1.0000x reference)
//
#include <hip/hip_runtime.h>
#include <math.h>

static constexpr int Bn   = 8192;
static constexpr int Kn   = 400;
static constexpr int NSn  = 20;
static constexpr int SECn = 20;
static constexpr int Sn   = Kn / SECn;     // 20 sections
static constexpr int NROWS = Bn * Kn;      // 3,276,800 rows for CE
static constexpr int NGRP  = Bn * Sn;      // 163,840 Procrustes groups

__device__ __forceinline__ float smooth_l1f(float x) {
    float ax = fabsf(x);
    return ax < 1.0f ? 0.5f * x * x : ax - 0.5f;
}

__global__ void zero_ws_kernel(float* ws) {
    if (threadIdx.x < 4) ws[threadIdx.x] = 0.0f;
}

// ---------------- Cross-entropy over [NROWS, 20] ----------------
__global__ __launch_bounds__(256) void ce_kernel(
    const float* __restrict__ logits,
    const int*   __restrict__ labels,
    float*       __restrict__ ws)
{
    int row = blockIdx.x * 256 + threadIdx.x;   // grid sized exactly
    const float4* p = reinterpret_cast<const float4*>(logits) + (size_t)row * 5;
    int lab = labels[row];

    float x[20];
#pragma unroll
    for (int i = 0; i < 5; i++) {
        float4 v = p[i];
        x[4*i+0] = v.x; x[4*i+1] = v.y; x[4*i+2] = v.z; x[4*i+3] = v.w;
    }
    float m = x[0];
#pragma unroll
    for (int i = 1; i < 20; i++) m = fmaxf(m, x[i]);
    float se = 0.0f;
    float xl = 0.0f;
#pragma unroll
    for (int i = 0; i < 20; i++) {
        se += __expf(x[i] - m);
        xl = (i == lab) ? x[i] : xl;     // avoid dynamic-index scratch
    }
    float nll = __logf(se) + m - xl;

    // block reduce: 4 waves
#pragma unroll
    for (int o = 32; o > 0; o >>= 1) nll += __shfl_down(nll, o);
    __shared__ float sm[4];
    int lane = threadIdx.x & 63, wid = threadIdx.x >> 6;
    if (lane == 0) sm[wid] = nll;
    __syncthreads();
    if (threadIdx.x == 0) {
        atomicAdd(&ws[0], sm[0] + sm[1] + sm[2] + sm[3]);
    }
}

// ------------- Keypoint + Procrustes + center losses -------------
__global__ __launch_bounds__(128, 2) void proc_kernel(
    const float* __restrict__ P,
    const float* __restrict__ G,
    float*       __restrict__ ws)
{
    int grp = blockIdx.x * 128 + threadIdx.x;   // grid sized exactly
    const float4* pp = reinterpret_cast<const float4*>(P) + (size_t)grp * 15;
    const float4* gg = reinterpret_cast<const float4*>(G) + (size_t)grp * 15;

    float p[60], g[60];
#pragma unroll
    for (int i = 0; i < 15; i++) {
        float4 v = pp[i];
        p[4*i+0] = v.x; p[4*i+1] = v.y; p[4*i+2] = v.z; p[4*i+3] = v.w;
    }
#pragma unroll
    for (int i = 0; i < 15; i++) {
        float4 v = gg[i];
        g[4*i+0] = v.x; g[4*i+1] = v.y; g[4*i+2] = v.z; g[4*i+3] = v.w;
    }

    // smooth-L1 keypoint partial over 60 elements
    float kp = 0.0f;
#pragma unroll
    for (int i = 0; i < 60; i++) kp += smooth_l1f(p[i] - g[i]);

    // means
    float sp0=0,sp1=0,sp2=0, sg0=0,sg1=0,sg2=0;
#pragma unroll
    for (int k = 0; k < 20; k++) {
        sp0 += p[3*k+0]; sp1 += p[3*k+1]; sp2 += p[3*k+2];
        sg0 += g[3*k+0]; sg1 += g[3*k+1]; sg2 += g[3*k+2];
    }
    const float inv20 = 1.0f / 20.0f;
    float mp0=sp0*inv20, mp1=sp1*inv20, mp2=sp2*inv20;
    float mg0=sg0*inv20, mg1=sg1*inv20, mg2=sg2*inv20;

    float cent = smooth_l1f(mp0-mg0) + smooth_l1f(mp1-mg1) + smooth_l1f(mp2-mg2);

    // H[i][j] = sum_k Gc[k][i] * Pc[k][j]
    float X[3][3] = {{0,0,0},{0,0,0},{0,0,0}};
#pragma unroll
    for (int k = 0; k < 20; k++) {
        float pc0 = p[3*k+0]-mp0, pc1 = p[3*k+1]-mp1, pc2 = p[3*k+2]-mp2;
        float gc0 = g[3*k+0]-mg0, gc1 = g[3*k+1]-mg1, gc2 = g[3*k+2]-mg2;
        X[0][0] += gc0*pc0; X[0][1] += gc0*pc1; X[0][2] += gc0*pc2;
        X[1][0] += gc1*pc0; X[1][1] += gc1*pc1; X[1][2] += gc1*pc2;
        X[2][0] += gc2*pc0; X[2][1] += gc2*pc1; X[2][2] += gc2*pc2;
    }

    // Polar factor R = U Vh via scaled Newton: X <- 0.5*(g*X + (1/(g*det))*Cof(X))
#pragma unroll
    for (int it = 0; it < 8; it++) {
        float c00 =  X[1][1]*X[2][2] - X[1][2]*X[2][1];
        float c01 = -(X[1][0]*X[2][2] - X[1][2]*X[2][0]);
        float c02 =  X[1][0]*X[2][1] - X[1][1]*X[2][0];
        float c10 = -(X[0][1]*X[2][2] - X[0][2]*X[2][1]);
        float c11 =  X[0][0]*X[2][2] - X[0][2]*X[2][0];
        float c12 = -(X[0][0]*X[2][1] - X[0][1]*X[2][0]);
        float c20 =  X[0][1]*X[1][2] - X[0][2]*X[1][1];
        float c21 = -(X[0][0]*X[1][2] - X[0][2]*X[1][0]);
        float c22 =  X[0][0]*X[1][1] - X[0][1]*X[1][0];
        float d = X[0][0]*c00 + X[0][1]*c01 + X[0][2]*c02;
        float ad = fmaxf(fabsf(d), 1e-30f);
        float gam = __powf(ad, -(1.0f/3.0f));            // |det|^(-1/3) scaling
        float dsn = (d < 0.0f) ? -ad : ad;
        float k1 = 0.5f * gam;
        float k2 = 0.5f / (gam * dsn);
        X[0][0] = k1*X[0][0] + k2*c00;  X[0][1] = k1*X[0][1] + k2*c01;  X[0][2] = k1*X[0][2] + k2*c02;
        X[1][0] = k1*X[1][0] + k2*c10;  X[1][1] = k1*X[1][1] + k2*c11;  X[1][2] = k1*X[1][2] + k2*c12;
        X[2][0] = k1*X[2][0] + k2*c20;  X[2][1] = k1*X[2][1] + k2*c21;  X[2][2] = k1*X[2][2] + k2*c22;
    }

    // pathological-safety: if Newton blew up (measure-zero event), fall back to identity
    float s9 = X[0][0]+X[0][1]+X[0][2]+X[1][0]+X[1][1]+X[1][2]+X[2][0]+X[2][1]+X[2][2];
    if (!(s9 == s9) || fabsf(s9) > 1e10f) {
        X[0][0]=1; X[0][1]=0; X[0][2]=0;
        X[1][0]=0; X[1][1]=1; X[1][2]=0;
        X[2][0]=0; X[2][1]=0; X[2][2]=1;
    }

    // rot partial: sum smooth_l1( Pc @ R - Gc )
    float rot = 0.0f;
#pragma unroll
    for (int k = 0; k < 20; k++) {
        float pc0 = p[3*k+0]-mp0, pc1 = p[3*k+1]-mp1, pc2 = p[3*k+2]-mp2;
        float gc0 = g[3*k+0]-mg0, gc1 = g[3*k+1]-mg1, gc2 = g[3*k+2]-mg2;
        float a0 = pc0*X[0][0] + pc1*X[1][0] + pc2*X[2][0] - gc0;
        float a1 = pc0*X[0][1] + pc1*X[1][1] + pc2*X[2][1] - gc1;
        float a2 = pc0*X[0][2] + pc1*X[1][2] + pc2*X[2][2] - gc2;
        rot += smooth_l1f(a0) + smooth_l1f(a1) + smooth_l1f(a2);
    }

    // block reduce (2 waves) for kp / rot / cent
#pragma unroll
    for (int o = 32; o > 0; o >>= 1) {
        kp   += __shfl_down(kp, o);
        rot  += __shfl_down(rot, o);
        cent += __shfl_down(cent, o);
    }
    __shared__ float sm[3][2];
    int lane = threadIdx.x & 63, wid = threadIdx.x >> 6;
    if (lane == 0) { sm[0][wid] = kp; sm[1][wid] = rot; sm[2][wid] = cent; }
    __syncthreads();
    if (threadIdx.x == 0) {
        atomicAdd(&ws[1], sm[0][0] + sm[0][1]);
        atomicAdd(&ws[2], sm[1][0] + sm[1][1]);
        atomicAdd(&ws[3], sm[2][0] + sm[2][1]);
    }
}

__global__ void finalize_kernel(const float* __restrict__ ws, float* __restrict__ out) {
    float section = ws[0] * (1.0f / (float)NROWS);            // /3,276,800
    float kp      = ws[1] * (1.0f / (float)(NROWS * 3));      // /9,830,400
    float rot     = ws[2] * (1.0f / (float)(NROWS * 3));      // same element count
    float cent    = ws[3] * (1.0f / (float)(Bn * Sn * 3));    // /491,520
    out[0] = section + 4.0f * kp + 5.0f * rot + 6.0f * cent;
}

extern "C" void kernel_launch(void* const* d_in, const int* in_sizes, int n_in,
                              void* d_out, int out_size, void* d_ws, size_t ws_size,
                              hipStream_t stream) {
    const float* pred_kp = (const float*)d_in[0];
    const float* gt_kp   = (const float*)d_in[1];
    const float* logits  = (const float*)d_in[2];
    const int*   labels  = (const int*)d_in[3];
    float* out = (float*)d_out;
    float* ws  = (float*)d_ws;

    zero_ws_kernel<<<1, 64, 0, stream>>>(ws);
    ce_kernel<<<NROWS / 256, 256, 0, stream>>>(logits, labels, ws);
    proc_kernel<<<NGRP / 128, 128, 0, stream>>>(pred_kp, gt_kp, ws);
    finalize_kernel<<<1, 1, 0, stream>>>(ws, out);
}

// Round 2
// 541.016 us; speedup vs baseline: 1.0231x; 1.0231x over previous
//
#include <hip/hip_runtime.h>
#include <math.h>

static constexpr int Bn   = 8192;
static constexpr int Kn   = 400;
static constexpr int SECn = 20;
static constexpr int Sn   = Kn / SECn;     // 20 sections
static constexpr int NROWS = Bn * Kn;      // 3,276,800 rows for CE
static constexpr int NGRP  = Bn * Sn;      // 163,840 Procrustes groups

__device__ __forceinline__ float smooth_l1f(float x) {
    float ax = fabsf(x);
    return ax < 1.0f ? 0.5f * x * x : ax - 0.5f;
}

__global__ void zero_ws_kernel(float* ws) {
    if (threadIdx.x < 4) ws[threadIdx.x] = 0.0f;
}

// ---------------- Cross-entropy over [NROWS, 20] ----------------
// Block = 256 threads = 256 rows. Stage 256x20 floats through LDS with
// coalesced float4 global loads; compute phase reads row at stride 21
// (coprime with 32 banks -> 2 lanes/bank = conflict-free).
__global__ __launch_bounds__(256) void ce_kernel(
    const float* __restrict__ logits,
    const int*   __restrict__ labels,
    float*       __restrict__ ws)
{
    __shared__ float lx[256 * 21];
    const int t = threadIdx.x;
    const size_t rowbase = (size_t)blockIdx.x * 256;
    const float4* __restrict__ src = reinterpret_cast<const float4*>(logits) + rowbase * 5;

#pragma unroll
    for (int i = 0; i < 5; i++) {
        int q = t + i * 256;            // float4 index within tile, coalesced
        float4 v = src[q];
        int row = q / 5, c4 = q % 5;    // each float4 lies within one row (20%4==0)
        float* d = &lx[row * 21 + c4 * 4];
        d[0] = v.x; d[1] = v.y; d[2] = v.z; d[3] = v.w;
    }
    __syncthreads();

    int lab = labels[rowbase + t];      // coalesced int load

    float x[20];
#pragma unroll
    for (int j = 0; j < 20; j++) x[j] = lx[t * 21 + j];

    float m = x[0];
#pragma unroll
    for (int j = 1; j < 20; j++) m = fmaxf(m, x[j]);
    float se = 0.0f, xl = 0.0f;
#pragma unroll
    for (int j = 0; j < 20; j++) {
        se += __expf(x[j] - m);
        xl = (j == lab) ? x[j] : xl;
    }
    float nll = __logf(se) + m - xl;

#pragma unroll
    for (int o = 32; o > 0; o >>= 1) nll += __shfl_down(nll, o);
    __shared__ float sm[4];
    int lane = t & 63, wid = t >> 6;
    if (lane == 0) sm[wid] = nll;
    __syncthreads();
    if (t == 0) atomicAdd(&ws[0], sm[0] + sm[1] + sm[2] + sm[3]);
}

// ------------- Keypoint + Procrustes + center losses -------------
// Block = 128 threads = 128 groups. Stage both 128x60 tiles through LDS
// (stride 61, conflict-free). LDS = 2*128*61*4 = 62464 B (< 64 KB).
__global__ __launch_bounds__(128) void proc_kernel(
    const float* __restrict__ P,
    const float* __restrict__ G,
    float*       __restrict__ ws)
{
    __shared__ float lp[128 * 61];
    __shared__ float lg[128 * 61];
    const int t = threadIdx.x;
    const size_t gbase = (size_t)blockIdx.x * 128;
    const float4* __restrict__ sp = reinterpret_cast<const float4*>(P) + gbase * 15;
    const float4* __restrict__ sg = reinterpret_cast<const float4*>(G) + gbase * 15;

#pragma unroll
    for (int i = 0; i < 15; i++) {
        int q = t + i * 128;            // coalesced float4 index
        int row = q / 15, c4 = q % 15;  // each float4 within one row (60%4==0)
        float4 v = sp[q];
        float* d = &lp[row * 61 + c4 * 4];
        d[0] = v.x; d[1] = v.y; d[2] = v.z; d[3] = v.w;
        float4 w = sg[q];
        float* e = &lg[row * 61 + c4 * 4];
        e[0] = w.x; e[1] = w.y; e[2] = w.z; e[3] = w.w;
    }
    __syncthreads();

    float p[60], g[60];
#pragma unroll
    for (int j = 0; j < 60; j++) p[j] = lp[t * 61 + j];
#pragma unroll
    for (int j = 0; j < 60; j++) g[j] = lg[t * 61 + j];

    // smooth-L1 keypoint partial over 60 elements
    float kp = 0.0f;
#pragma unroll
    for (int i = 0; i < 60; i++) kp += smooth_l1f(p[i] - g[i]);

    // means
    float sp0=0,sp1=0,sp2=0, sg0=0,sg1=0,sg2=0;
#pragma unroll
    for (int k = 0; k < 20; k++) {
        sp0 += p[3*k+0]; sp1 += p[3*k+1]; sp2 += p[3*k+2];
        sg0 += g[3*k+0]; sg1 += g[3*k+1]; sg2 += g[3*k+2];
    }
    const float inv20 = 1.0f / 20.0f;
    float mp0=sp0*inv20, mp1=sp1*inv20, mp2=sp2*inv20;
    float mg0=sg0*inv20, mg1=sg1*inv20, mg2=sg2*inv20;

    float cent = smooth_l1f(mp0-mg0) + smooth_l1f(mp1-mg1) + smooth_l1f(mp2-mg2);

    // H[i][j] = sum_k Gc[k][i] * Pc[k][j]
    float X[3][3] = {{0,0,0},{0,0,0},{0,0,0}};
#pragma unroll
    for (int k = 0; k < 20; k++) {
        float pc0 = p[3*k+0]-mp0, pc1 = p[3*k+1]-mp1, pc2 = p[3*k+2]-mp2;
        float gc0 = g[3*k+0]-mg0, gc1 = g[3*k+1]-mg1, gc2 = g[3*k+2]-mg2;
        X[0][0] += gc0*pc0; X[0][1] += gc0*pc1; X[0][2] += gc0*pc2;
        X[1][0] += gc1*pc0; X[1][1] += gc1*pc1; X[1][2] += gc1*pc2;
        X[2][0] += gc2*pc0; X[2][1] += gc2*pc1; X[2][2] += gc2*pc2;
    }

    // Polar factor R = U Vh via scaled Newton: X <- 0.5*(g*X + (1/(g*det))*Cof(X))
#pragma unroll
    for (int it = 0; it < 8; it++) {
        float c00 =  X[1][1]*X[2][2] - X[1][2]*X[2][1];
        float c01 = -(X[1][0]*X[2][2] - X[1][2]*X[2][0]);
        float c02 =  X[1][0]*X[2][1] - X[1][1]*X[2][0];
        float c10 = -(X[0][1]*X[2][2] - X[0][2]*X[2][1]);
        float c11 =  X[0][0]*X[2][2] - X[0][2]*X[2][0];
        float c12 = -(X[0][0]*X[2][1] - X[0][1]*X[2][0]);
        float c20 =  X[0][1]*X[1][2] - X[0][2]*X[1][1];
        float c21 = -(X[0][0]*X[1][2] - X[0][2]*X[1][0]);
        float c22 =  X[0][0]*X[1][1] - X[0][1]*X[1][0];
        float d = X[0][0]*c00 + X[0][1]*c01 + X[0][2]*c02;
        float ad = fmaxf(fabsf(d), 1e-30f);
        float gam = __powf(ad, -(1.0f/3.0f));            // |det|^(-1/3) scaling
        float dsn = (d < 0.0f) ? -ad : ad;
        float k1 = 0.5f * gam;
        float k2 = 0.5f / (gam * dsn);
        X[0][0] = k1*X[0][0] + k2*c00;  X[0][1] = k1*X[0][1] + k2*c01;  X[0][2] = k1*X[0][2] + k2*c02;
        X[1][0] = k1*X[1][0] + k2*c10;  X[1][1] = k1*X[1][1] + k2*c11;  X[1][2] = k1*X[1][2] + k2*c12;
        X[2][0] = k1*X[2][0] + k2*c20;  X[2][1] = k1*X[2][1] + k2*c21;  X[2][2] = k1*X[2][2] + k2*c22;
    }

    // pathological-safety: if Newton blew up (measure-zero event), use identity
    float s9 = X[0][0]+X[0][1]+X[0][2]+X[1][0]+X[1][1]+X[1][2]+X[2][0]+X[2][1]+X[2][2];
    if (!(s9 == s9) || fabsf(s9) > 1e10f) {
        X[0][0]=1; X[0][1]=0; X[0][2]=0;
        X[1][0]=0; X[1][1]=1; X[1][2]=0;
        X[2][0]=0; X[2][1]=0; X[2][2]=1;
    }

    // rot partial: sum smooth_l1( Pc @ R - Gc )
    float rot = 0.0f;
#pragma unroll
    for (int k = 0; k < 20; k++) {
        float pc0 = p[3*k+0]-mp0, pc1 = p[3*k+1]-mp1, pc2 = p[3*k+2]-mp2;
        float gc0 = g[3*k+0]-mg0, gc1 = g[3*k+1]-mg1, gc2 = g[3*k+2]-mg2;
        float a0 = pc0*X[0][0] + pc1*X[1][0] + pc2*X[2][0] - gc0;
        float a1 = pc0*X[0][1] + pc1*X[1][1] + pc2*X[2][1] - gc1;
        float a2 = pc0*X[0][2] + pc1*X[1][2] + pc2*X[2][2] - gc2;
        rot += smooth_l1f(a0) + smooth_l1f(a1) + smooth_l1f(a2);
    }

    // block reduce (2 waves)
#pragma unroll
    for (int o = 32; o > 0; o >>= 1) {
        kp   += __shfl_down(kp, o);
        rot  += __shfl_down(rot, o);
        cent += __shfl_down(cent, o);
    }
    __shared__ float sm[3][2];
    int lane = t & 63, wid = t >> 6;
    if (lane == 0) { sm[0][wid] = kp; sm[1][wid] = rot; sm[2][wid] = cent; }
    __syncthreads();
    if (t == 0) {
        atomicAdd(&ws[1], sm[0][0] + sm[0][1]);
        atomicAdd(&ws[2], sm[1][0] + sm[1][1]);
        atomicAdd(&ws[3], sm[2][0] + sm[2][1]);
    }
}

__global__ void finalize_kernel(const float* __restrict__ ws, float* __restrict__ out) {
    float section = ws[0] * (1.0f / (float)NROWS);
    float kp      = ws[1] * (1.0f / (float)(NROWS * 3));
    float rot     = ws[2] * (1.0f / (float)(NROWS * 3));
    float cent    = ws[3] * (1.0f / (float)(Bn * Sn * 3));
    out[0] = section + 4.0f * kp + 5.0f * rot + 6.0f * cent;
}

extern "C" void kernel_launch(void* const* d_in, const int* in_sizes, int n_in,
                              void* d_out, int out_size, void* d_ws, size_t ws_size,
                              hipStream_t stream) {
    const float* pred_kp = (const float*)d_in[0];
    const float* gt_kp   = (const float*)d_in[1];
    const float* logits  = (const float*)d_in[2];
    const int*   labels  = (const int*)d_in[3];
    float* out = (float*)d_out;
    float* ws  = (float*)d_ws;

    zero_ws_kernel<<<1, 64, 0, stream>>>(ws);
    ce_kernel<<<NROWS / 256, 256, 0, stream>>>(logits, labels, ws);
    proc_kernel<<<NGRP / 128, 128, 0, stream>>>(pred_kp, gt_kp, ws);
    finalize_kernel<<<1, 1, 0, stream>>>(ws, out);
}

// Round 3
// 469.707 us; speedup vs baseline: 1.1785x; 1.1518x over previous
//
#include <hip/hip_runtime.h>
#include <math.h>

static constexpr int Bn    = 8192;
static constexpr int Kn    = 400;
static constexpr int Sn    = 20;                 // sections per batch
static constexpr int NROWS = Bn * Kn;            // 3,276,800 CE rows
static constexpr int NGRP  = Bn * Sn;            // 163,840 Procrustes groups

static constexpr int CE_BLOCKS = 2560, CE_TPB = 256, CE_RPT = 5;  // 2560*256*5 = NROWS
static constexpr int PR_BLOCKS = 640,  PR_TPB = 256;              // 640*256    = NGRP

// ws layout (floats): all slots below are written unconditionally each call,
// so no zero-init is needed despite the 0xAA poison.
static constexpr int WS_CE   = 0;      // [2560]
static constexpr int WS_KP   = 4096;   // [640]
static constexpr int WS_ROT  = 8192;   // [640]
static constexpr int WS_CENT = 12288;  // [640]

__device__ __forceinline__ float smooth_l1f(float x) {
    float ax = fabsf(x);
    return ax < 1.0f ? 0.5f * x * x : ax - 0.5f;
}

// ---------------- Cross-entropy over [NROWS, 20] ----------------
// No atomics: per-block partial -> ws[WS_CE + blockIdx.x].
__global__ __launch_bounds__(256) void ce_kernel(
    const float* __restrict__ logits,
    const int*   __restrict__ labels,
    float*       __restrict__ ws)
{
    const int t = threadIdx.x;
    const size_t tid  = (size_t)blockIdx.x * CE_TPB + t;
    const size_t row0 = tid * CE_RPT;
    const float4* __restrict__ src = reinterpret_cast<const float4*>(logits) + row0 * 5;

    float acc = 0.0f;
#pragma unroll
    for (int r = 0; r < CE_RPT; r++) {
        float x[20];
#pragma unroll
        for (int i = 0; i < 5; i++) {
            float4 v = src[r * 5 + i];
            x[4*i+0] = v.x; x[4*i+1] = v.y; x[4*i+2] = v.z; x[4*i+3] = v.w;
        }
        int lab = labels[row0 + r];
        float m = x[0];
#pragma unroll
        for (int j = 1; j < 20; j++) m = fmaxf(m, x[j]);
        float se = 0.0f, xl = 0.0f;
#pragma unroll
        for (int j = 0; j < 20; j++) {
            se += __expf(x[j] - m);
            xl = (j == lab) ? x[j] : xl;
        }
        acc += __logf(se) + m - xl;
    }

    // block reduce (4 waves)
#pragma unroll
    for (int o = 32; o > 0; o >>= 1) acc += __shfl_down(acc, o);
    __shared__ float sm[4];
    int lane = t & 63, wid = t >> 6;
    if (lane == 0) sm[wid] = acc;
    __syncthreads();
    if (t == 0) ws[WS_CE + blockIdx.x] = sm[0] + sm[1] + sm[2] + sm[3];
}

// ------------- Keypoint + Procrustes + center losses -------------
// 1 thread per group, 3 streaming passes over the group's 15 float4s
// (passes 2-3 hit L1/L2). Low VGPR: no 60-element register arrays.
__global__ __launch_bounds__(256) void proc_kernel(
    const float* __restrict__ P,
    const float* __restrict__ G,
    float*       __restrict__ ws)
{
    const int t = threadIdx.x;
    const int grp = blockIdx.x * PR_TPB + t;
    const float4* __restrict__ pp = reinterpret_cast<const float4*>(P) + (size_t)grp * 15;
    const float4* __restrict__ gg = reinterpret_cast<const float4*>(G) + (size_t)grp * 15;

    // Pass A: keypoint smooth-L1 + coordinate sums
    float kp = 0.0f;
    float sp[3] = {0,0,0}, sg[3] = {0,0,0};
#pragma unroll
    for (int i = 0; i < 15; i++) {
        float4 a = pp[i], b = gg[i];
        float av[4] = {a.x, a.y, a.z, a.w};
        float bv[4] = {b.x, b.y, b.z, b.w};
#pragma unroll
        for (int j = 0; j < 4; j++) {
            int c = (4*i + j) % 3;               // compile-time after unroll
            kp += smooth_l1f(av[j] - bv[j]);
            sp[c] += av[j]; sg[c] += bv[j];
        }
    }
    const float inv20 = 1.0f / 20.0f;
    float mp[3] = {sp[0]*inv20, sp[1]*inv20, sp[2]*inv20};
    float mg[3] = {sg[0]*inv20, sg[1]*inv20, sg[2]*inv20};
    float cent = smooth_l1f(mp[0]-mg[0]) + smooth_l1f(mp[1]-mg[1]) + smooth_l1f(mp[2]-mg[2]);

    // Pass B: H[i][j] = sum_pt Gc[pt][i]*Pc[pt][j], in 4-point (3-float4) chunks
    float X[3][3] = {{0,0,0},{0,0,0},{0,0,0}};
#pragma unroll
    for (int ch = 0; ch < 5; ch++) {
        float4 a0 = pp[3*ch+0], a1 = pp[3*ch+1], a2 = pp[3*ch+2];
        float4 b0 = gg[3*ch+0], b1 = gg[3*ch+1], b2 = gg[3*ch+2];
        float pv[12] = {a0.x,a0.y,a0.z,a0.w, a1.x,a1.y,a1.z,a1.w, a2.x,a2.y,a2.z,a2.w};
        float gv[12] = {b0.x,b0.y,b0.z,b0.w, b1.x,b1.y,b1.z,b1.w, b2.x,b2.y,b2.z,b2.w};
#pragma unroll
        for (int q = 0; q < 4; q++) {
            float pc0 = pv[3*q+0]-mp[0], pc1 = pv[3*q+1]-mp[1], pc2 = pv[3*q+2]-mp[2];
            float gc0 = gv[3*q+0]-mg[0], gc1 = gv[3*q+1]-mg[1], gc2 = gv[3*q+2]-mg[2];
            X[0][0] += gc0*pc0; X[0][1] += gc0*pc1; X[0][2] += gc0*pc2;
            X[1][0] += gc1*pc0; X[1][1] += gc1*pc1; X[1][2] += gc1*pc2;
            X[2][0] += gc2*pc0; X[2][1] += gc2*pc1; X[2][2] += gc2*pc2;
        }
    }

    // Polar factor R = U Vh via det-scaled Newton
#pragma unroll
    for (int it = 0; it < 8; it++) {
        float c00 =  X[1][1]*X[2][2] - X[1][2]*X[2][1];
        float c01 = -(X[1][0]*X[2][2] - X[1][2]*X[2][0]);
        float c02 =  X[1][0]*X[2][1] - X[1][1]*X[2][0];
        float c10 = -(X[0][1]*X[2][2] - X[0][2]*X[2][1]);
        float c11 =  X[0][0]*X[2][2] - X[0][2]*X[2][0];
        float c12 = -(X[0][0]*X[2][1] - X[0][1]*X[2][0]);
        float c20 =  X[0][1]*X[1][2] - X[0][2]*X[1][1];
        float c21 = -(X[0][0]*X[1][2] - X[0][2]*X[1][0]);
        float c22 =  X[0][0]*X[1][1] - X[0][1]*X[1][0];
        float d = X[0][0]*c00 + X[0][1]*c01 + X[0][2]*c02;
        float ad = fmaxf(fabsf(d), 1e-30f);
        float gam = __powf(ad, -(1.0f/3.0f));
        float dsn = (d < 0.0f) ? -ad : ad;
        float k1 = 0.5f * gam;
        float k2 = 0.5f / (gam * dsn);
        X[0][0] = k1*X[0][0] + k2*c00;  X[0][1] = k1*X[0][1] + k2*c01;  X[0][2] = k1*X[0][2] + k2*c02;
        X[1][0] = k1*X[1][0] + k2*c10;  X[1][1] = k1*X[1][1] + k2*c11;  X[1][2] = k1*X[1][2] + k2*c12;
        X[2][0] = k1*X[2][0] + k2*c20;  X[2][1] = k1*X[2][1] + k2*c21;  X[2][2] = k1*X[2][2] + k2*c22;
    }
    float s9 = X[0][0]+X[0][1]+X[0][2]+X[1][0]+X[1][1]+X[1][2]+X[2][0]+X[2][1]+X[2][2];
    if (!(s9 == s9) || fabsf(s9) > 1e10f) {
        X[0][0]=1; X[0][1]=0; X[0][2]=0;
        X[1][0]=0; X[1][1]=1; X[1][2]=0;
        X[2][0]=0; X[2][1]=0; X[2][2]=1;
    }

    // Pass C: rot = sum smooth_l1( Pc @ R - Gc ), same 4-point chunking
    float rot = 0.0f;
#pragma unroll
    for (int ch = 0; ch < 5; ch++) {
        float4 a0 = pp[3*ch+0], a1 = pp[3*ch+1], a2 = pp[3*ch+2];
        float4 b0 = gg[3*ch+0], b1 = gg[3*ch+1], b2 = gg[3*ch+2];
        float pv[12] = {a0.x,a0.y,a0.z,a0.w, a1.x,a1.y,a1.z,a1.w, a2.x,a2.y,a2.z,a2.w};
        float gv[12] = {b0.x,b0.y,b0.z,b0.w, b1.x,b1.y,b1.z,b1.w, b2.x,b2.y,b2.z,b2.w};
#pragma unroll
        for (int q = 0; q < 4; q++) {
            float pc0 = pv[3*q+0]-mp[0], pc1 = pv[3*q+1]-mp[1], pc2 = pv[3*q+2]-mp[2];
            float gc0 = gv[3*q+0]-mg[0], gc1 = gv[3*q+1]-mg[1], gc2 = gv[3*q+2]-mg[2];
            float a0r = pc0*X[0][0] + pc1*X[1][0] + pc2*X[2][0] - gc0;
            float a1r = pc0*X[0][1] + pc1*X[1][1] + pc2*X[2][1] - gc1;
            float a2r = pc0*X[0][2] + pc1*X[1][2] + pc2*X[2][2] - gc2;
            rot += smooth_l1f(a0r) + smooth_l1f(a1r) + smooth_l1f(a2r);
        }
    }

    // block reduce (4 waves), then per-block partial stores (no atomics)
#pragma unroll
    for (int o = 32; o > 0; o >>= 1) {
        kp   += __shfl_down(kp, o);
        rot  += __shfl_down(rot, o);
        cent += __shfl_down(cent, o);
    }
    __shared__ float sm[3][4];
    int lane = t & 63, wid = t >> 6;
    if (lane == 0) { sm[0][wid] = kp; sm[1][wid] = rot; sm[2][wid] = cent; }
    __syncthreads();
    if (t == 0) {
        ws[WS_KP   + blockIdx.x] = sm[0][0] + sm[0][1] + sm[0][2] + sm[0][3];
        ws[WS_ROT  + blockIdx.x] = sm[1][0] + sm[1][1] + sm[1][2] + sm[1][3];
        ws[WS_CENT + blockIdx.x] = sm[2][0] + sm[2][1] + sm[2][2] + sm[2][3];
    }
}

// ---------------- Final reduction of per-block partials ----------------
__global__ __launch_bounds__(256) void reduce_kernel(
    const float* __restrict__ ws, float* __restrict__ out)
{
    const int t = threadIdx.x;
    float s_ce = 0, s_kp = 0, s_rot = 0, s_cent = 0;
    for (int i = t; i < CE_BLOCKS; i += 256) s_ce += ws[WS_CE + i];
    for (int i = t; i < PR_BLOCKS; i += 256) {
        s_kp   += ws[WS_KP + i];
        s_rot  += ws[WS_ROT + i];
        s_cent += ws[WS_CENT + i];
    }
#pragma unroll
    for (int o = 32; o > 0; o >>= 1) {
        s_ce   += __shfl_down(s_ce, o);
        s_kp   += __shfl_down(s_kp, o);
        s_rot  += __shfl_down(s_rot, o);
        s_cent += __shfl_down(s_cent, o);
    }
    __shared__ float sm[4][4];
    int lane = t & 63, wid = t >> 6;
    if (lane == 0) { sm[0][wid]=s_ce; sm[1][wid]=s_kp; sm[2][wid]=s_rot; sm[3][wid]=s_cent; }
    __syncthreads();
    if (t == 0) {
        float ce   = (sm[0][0]+sm[0][1]+sm[0][2]+sm[0][3]) * (1.0f / (float)NROWS);
        float kp   = (sm[1][0]+sm[1][1]+sm[1][2]+sm[1][3]) * (1.0f / (float)(NROWS * 3));
        float rot  = (sm[2][0]+sm[2][1]+sm[2][2]+sm[2][3]) * (1.0f / (float)(NROWS * 3));
        float cent = (sm[3][0]+sm[3][1]+sm[3][2]+sm[3][3]) * (1.0f / (float)(NGRP * 3));
        out[0] = ce + 4.0f * kp + 5.0f * rot + 6.0f * cent;
    }
}

extern "C" void kernel_launch(void* const* d_in, const int* in_sizes, int n_in,
                              void* d_out, int out_size, void* d_ws, size_t ws_size,
                              hipStream_t stream) {
    const float* pred_kp = (const float*)d_in[0];
    const float* gt_kp   = (const float*)d_in[1];
    const float* logits  = (const float*)d_in[2];
    const int*   labels  = (const int*)d_in[3];
    float* out = (float*)d_out;
    float* ws  = (float*)d_ws;

    ce_kernel<<<CE_BLOCKS, CE_TPB, 0, stream>>>(logits, labels, ws);
    proc_kernel<<<PR_BLOCKS, PR_TPB, 0, stream>>>(pred_kp, gt_kp, ws);
    reduce_kernel<<<1, 256, 0, stream>>>(ws, out);
}